// Round 10
// baseline (280.081 us; speedup 1.0000x reference)
//
#include <hip/hip_runtime.h>

// ============================================================================
// CrossAttention fused: qkv proj (bf16 MFMA) -> flash attn -> out proj + bias
// B=2, NQ=2048, NK=4096, D=1024, H=16, HD=64, SCALE=0.125, mask-then-scale
//
// v11: attn K/V staging via global_load_lds with per-lane pre-swizzled SOURCE
// addresses (linear LDS dest, XOR-granule spread on reads) -- deletes all
// attn LDS stores + staging regs. V is produced TRANSPOSED (vh_t[bh][d][key])
// by proj_fused seg2 using the swapped-MFMA trick (C^T in regs, same-coalesced
// epilogue). Fixed-max softmax, double-buffer 1-barrier/tile kept from v8.
// ============================================================================

typedef __attribute__((ext_vector_type(8))) short bf16x8;
typedef __attribute__((ext_vector_type(4))) short bf16x4;
typedef __attribute__((ext_vector_type(4))) float f32x4;
typedef __attribute__((ext_vector_type(4))) unsigned short u16x4;
typedef unsigned short u16;
typedef unsigned char u8;

#define DEV __device__ __forceinline__

DEV u16 f2bf(float f) {
  union { float f; unsigned int u; } x; x.f = f;
  unsigned int u = x.u;
  return (u16)((u + 0x7fffu + ((u >> 16) & 1u)) >> 16);
}

DEV unsigned cvt_pk_bf16(float lo, float hi) {
  unsigned r;
  asm("v_cvt_pk_bf16_f32 %0, %1, %2" : "=v"(r) : "v"(lo), "v"(hi));
  return r;
}

DEV u16x4 cvt4_bf16(float4 v) {
  union { unsigned u[2]; u16x4 s; } uu;
  uu.u[0] = cvt_pk_bf16(v.x, v.y);
  uu.u[1] = cvt_pk_bf16(v.z, v.w);
  return uu.s;
}

// async global->LDS, 16 bytes per lane; dst must be linear (base + lane*16)
DEV void gload16(const void* g, void* l) {
  __builtin_amdgcn_global_load_lds(
      (const __attribute__((address_space(1))) void*)g,
      (__attribute__((address_space(3))) void*)l, 16, 0, 0);
}

// mask-then-scale in log2 domain; fixed softmax shift M=16 folded into bias.
#define MASK_BIAS (-1.8033688e19f)
#define FREE_BIAS (-16.0f)
#define SCALE_LOG2E 0.18033688f

// ---------------------------------------------------------------------------
// Mask decode -> f32 additive log2-bias: MASK_BIAS if masked, -16 otherwise.
// ---------------------------------------------------------------------------
__global__ void decode_mask_k(const u8* __restrict__ raw, float* __restrict__ biasf, int n) {
  int t = threadIdx.x;
  int f_off = 0, f_gt1 = 0, f_80 = 0;
  for (int i = t; i < n; i += 256) {
    u8 bv = raw[i];
    if (bv > 1) f_gt1 = 1;
    if ((i & 3) && bv) f_off = 1;
    if (((i & 3) == 0) && bv == 0x80) f_80 = 1;
  }
  int g_gt1 = __syncthreads_or(f_gt1);
  int g_off = __syncthreads_or(f_off);
  int g_80  = __syncthreads_or(f_80);
  for (int i = t; i < n; i += 256) {
    int v;
    if (g_gt1) {
      if (g_80) v = (((const u16*)raw)[i] != 0) ? 1 : 0;      // bf16 storage
      else      v = (((const float*)raw)[i] != 0.0f) ? 1 : 0; // f32 storage
    } else if (g_off) {
      v = raw[i] ? 1 : 0;                                     // bool/u8 storage
    } else {
      v = (((const int*)raw)[i] != 0) ? 1 : 0;                // int32 storage
    }
    biasf[i] = v ? MASK_BIAS : FREE_BIAS;
  }
}

// ---------------------------------------------------------------------------
// Bulk fp32 -> bf16 convert (RNE). Segments: Wq,Wk,Wv,Wp then q,k,v.
// ---------------------------------------------------------------------------
__global__ void cvt_all_k(
    const float* __restrict__ Wq, const float* __restrict__ Wk,
    const float* __restrict__ Wv, const float* __restrict__ Wp,
    const float* __restrict__ q, const float* __restrict__ k, const float* __restrict__ v,
    u16* __restrict__ wqb, u16* __restrict__ wkb, u16* __restrict__ wvb, u16* __restrict__ wpb,
    u16* __restrict__ qb, u16* __restrict__ kb, u16* __restrict__ vb, int total)
{
  int stride = gridDim.x * blockDim.x;
  for (int idx = blockIdx.x * blockDim.x + threadIdx.x; idx < total; idx += stride) {
    const float* src; u16* dst; int off;
    if (idx < 131072)       { src = Wq; dst = wqb; off = idx; }
    else if (idx < 262144)  { src = Wk; dst = wkb; off = idx - 131072; }
    else if (idx < 393216)  { src = Wv; dst = wvb; off = idx - 262144; }
    else if (idx < 524288)  { src = Wp; dst = wpb; off = idx - 393216; }
    else if (idx < 1048576) { src = q;  dst = qb;  off = idx - 524288; }
    else if (idx < 2097152) { src = k;  dst = kb;  off = idx - 1048576; }
    else                    { src = v;  dst = vb;  off = idx - 2097152; }
    float4 a = *reinterpret_cast<const float4*>(src + (size_t)off * 8);
    float4 b = *reinterpret_cast<const float4*>(src + (size_t)off * 8 + 4);
    union { unsigned u[4]; uint4 q4; } o;
    o.u[0] = cvt_pk_bf16(a.x, a.y); o.u[1] = cvt_pk_bf16(a.z, a.w);
    o.u[2] = cvt_pk_bf16(b.x, b.y); o.u[3] = cvt_pk_bf16(b.z, b.w);
    *reinterpret_cast<uint4*>(dst + (size_t)off * 8) = o.q4;
  }
}

// ---------------------------------------------------------------------------
// Fused QKV projection GEMM. Grid 1280: [0,256)=q, [256,768)=k, [768,1280)=v.
// 128x128 tile, BK=32, 4 waves, global_load_lds staging (linear LDS).
// seg 0/1: C = A*W^T, output bf16 head layout [b,h,seq,64].
// seg 2 (V): SWAPPED MFMA -> C^T in regs; output TRANSPOSED vh_t[bh][d][key].
// ---------------------------------------------------------------------------
template <bool ABF>
__global__ __launch_bounds__(256) void proj_fused(
    const float* __restrict__ qf32, const float* __restrict__ kf32, const float* __restrict__ vf32,
    const u16* __restrict__ qb, const u16* __restrict__ kb, const u16* __restrict__ vb,
    const u16* __restrict__ wqb, const u16* __restrict__ wkb, const u16* __restrict__ wvb,
    u16* __restrict__ qh, u16* __restrict__ kh, u16* __restrict__ vh)
{
  constexpr int K = 1024;
  __shared__ __align__(16) u16 As[128 * 32];   // linear, 64 B rows
  __shared__ __align__(16) u16 Bs[128 * 32];
  const int tid = threadIdx.x;
  const int lane = tid & 63;
  const int w = tid >> 6;
  const int wm = w >> 1, wn = w & 1;
  const int l15 = lane & 15, lg = lane >> 4;

  int bid = blockIdx.x;
  bid = (bid & 7) * 160 + (bid >> 3);
  int seg, local;
  if (bid < 256)      { seg = 0; local = bid; }
  else if (bid < 768) { seg = 1; local = bid - 256; }
  else                { seg = 2; local = bid - 768; }
  const int bm = local >> 3, bn = local & 7;
  const float* Af = seg == 0 ? qf32 : (seg == 1 ? kf32 : vf32);
  const u16* Ab   = seg == 0 ? qb   : (seg == 1 ? kb   : vb);
  const u16* Wb   = seg == 0 ? wqb  : (seg == 1 ? wkb  : wvb);

  f32x4 acc[4][4] = {};

  for (int k0 = 0; k0 < K; k0 += 32) {
    __syncthreads();
    if constexpr (ABF) {
#pragma unroll
      for (int i = 0; i < 2; ++i) {
        int f = tid + 256 * i;
        int row = f >> 2, c = f & 3;
        gload16(Ab + (size_t)(bm * 128 + row) * K + k0 + c * 8, (char*)As + f * 16);
        gload16(Wb + (size_t)(bn * 128 + row) * K + k0 + c * 8, (char*)Bs + f * 16);
      }
    } else {
#pragma unroll
      for (int i = 0; i < 2; ++i) {
        int f = tid + 256 * i;
        int row = f >> 2, c = f & 3;
        gload16(Wb + (size_t)(bn * 128 + row) * K + k0 + c * 8, (char*)Bs + f * 16);
      }
#pragma unroll
      for (int i = 0; i < 4; ++i) {
        int f = tid + 256 * i;
        int row = f >> 3, c4 = f & 7;
        float4 va = *reinterpret_cast<const float4*>(Af + (size_t)(bm * 128 + row) * K + k0 + c4 * 4);
        *reinterpret_cast<u16x4*>((char*)As + row * 64 + c4 * 8) = cvt4_bf16(va);
      }
    }
    __syncthreads();

    bf16x8 af[4], bfr[4];
#pragma unroll
    for (int mi = 0; mi < 4; ++mi)
      af[mi] = *reinterpret_cast<const bf16x8*>((const char*)As + (wm * 64 + mi * 16 + l15) * 64 + lg * 16);
#pragma unroll
    for (int ni = 0; ni < 4; ++ni)
      bfr[ni] = *reinterpret_cast<const bf16x8*>((const char*)Bs + (wn * 64 + ni * 16 + l15) * 64 + lg * 16);
    if (seg == 2) {
      // swapped: acc[ni][mi] holds C^T (row = n via lg*4+r, col = m via l15)
#pragma unroll
      for (int ni = 0; ni < 4; ++ni)
#pragma unroll
        for (int mi = 0; mi < 4; ++mi)
          acc[ni][mi] = __builtin_amdgcn_mfma_f32_16x16x32_bf16(bfr[ni], af[mi], acc[ni][mi], 0, 0, 0);
    } else {
#pragma unroll
      for (int mi = 0; mi < 4; ++mi)
#pragma unroll
        for (int ni = 0; ni < 4; ++ni)
          acc[mi][ni] = __builtin_amdgcn_mfma_f32_16x16x32_bf16(af[mi], bfr[ni], acc[mi][ni], 0, 0, 0);
    }
  }

  if (seg == 2) {
    // C^T element: n = bn*128+wn*64+ni*16+lg*4+r (-> h,d); m = bm*128+wm*64+mi*16+l15 (-> b,key)
#pragma unroll
    for (int ni = 0; ni < 4; ++ni)
#pragma unroll
      for (int mi = 0; mi < 4; ++mi)
#pragma unroll
        for (int r = 0; r < 4; ++r) {
          int nn = bn * 128 + wn * 64 + ni * 16 + lg * 4 + r;
          int mm = bm * 128 + wm * 64 + mi * 16 + l15;
          int h = nn >> 6, d = nn & 63;
          int bb = mm >> 12, key = mm & 4095;
          vh[(((size_t)(bb * 16 + h)) * 64 + d) * 4096 + key] = f2bf(acc[ni][mi][r]);
        }
  } else {
    const int sl = (seg == 0) ? 11 : 12;
    u16* outh = (seg == 0) ? qh : kh;
    const int seqmask = (1 << sl) - 1;
#pragma unroll
    for (int mi = 0; mi < 4; ++mi)
#pragma unroll
      for (int ni = 0; ni < 4; ++ni)
#pragma unroll
        for (int r = 0; r < 4; ++r) {
          int m = bm * 128 + wm * 64 + mi * 16 + lg * 4 + r;
          int n = bn * 128 + wn * 64 + ni * 16 + l15;
          int b = m >> sl, ml = m & seqmask;
          int h = n >> 6, hd = n & 63;
          outh[((((size_t)b * 16 + h) << sl) + ml) * 64 + hd] = f2bf(acc[mi][ni][r]);
        }
  }
}

// ---------------------------------------------------------------------------
// Flash attention v11. 1 block = (b, h, 128-row q-tile); 4 waves x 32 q-rows.
// K/V staged via global_load_lds: linear LDS [64][64] per tile, per-lane
// source-XOR (granule g <- g^(row&7)); reads apply the same XOR. V sourced
// from transposed vh_t[bh][d][key]. Fixed-max softmax; dbuf, 1 barrier/tile.
// ---------------------------------------------------------------------------
__global__ __launch_bounds__(256) void attn_k(
    const u16* __restrict__ qh, const u16* __restrict__ kh, const u16* __restrict__ vh,
    const float* __restrict__ biasf, u16* __restrict__ ao)
{
  // 2 buffers x (K 8192B + V 8192B) = 32768 B
  __shared__ __align__(16) u16 lds[16384];

  const int tid = threadIdx.x;
  const int lane = tid & 63;
  const int w = tid >> 6;
  const int l15 = lane & 15, lg = lane >> 4;

  int bid = blockIdx.x;
  bid = (bid & 7) * 64 + (bid >> 3);
  const int qt = bid & 15;
  const int bh = bid >> 4;
  const int b = bh >> 4, h = bh & 15;

  const u16* kbase = kh + (size_t)bh * 4096 * 64;   // [key][d]
  const u16* vtbase = vh + (size_t)bh * 64 * 4096;  // [d][key]

  bf16x8 qf0[2], qf1[2];
  {
    const u16* qp0 = qh + ((size_t)bh * 2048 + (size_t)qt * 128 + w * 16 + l15) * 64 + lg * 8;
    qf0[0] = *reinterpret_cast<const bf16x8*>(qp0);
    qf0[1] = *reinterpret_cast<const bf16x8*>(qp0 + 32);
    const u16* qp1 = qp0 + 64 * 64;
    qf1[0] = *reinterpret_cast<const bf16x8*>(qp1);
    qf1[1] = *reinterpret_cast<const bf16x8*>(qp1 + 32);
  }

  f32x4 o0[4] = {}, o1[4] = {};
  float lac0 = 0.f, lac1 = 0.f;
  const float* bpt = biasf + b * 4096 + lg * 4;

  // staging source offsets (elems): chunk f -> (row = f>>3, g = f&7),
  // source granule g ^ (row&7); K row stride 64, V(d) row stride 4096.
  int ksrc[2], vsrc[2];
#pragma unroll
  for (int i = 0; i < 2; ++i) {
    int f = tid + 256 * i;
    int row = f >> 3, g = f & 7;
    int gs = (g ^ (row & 7)) * 8;
    ksrc[i] = row * 64 + gs;
    vsrc[i] = row * 4096 + gs;
  }

  // read offsets (bytes within each 8192B tile)
  int krd[4][2];
#pragma unroll
  for (int n = 0; n < 4; ++n)
#pragma unroll
    for (int kk = 0; kk < 2; ++kk) {
      int row = n * 16 + l15;
      krd[n][kk] = row * 128 + (((kk * 4 + lg) ^ (row & 7)) << 4);
    }
  int vrd[4][4];
#pragma unroll
  for (int dt = 0; dt < 4; ++dt)
#pragma unroll
    for (int n = 0; n < 4; ++n) {
      int d = dt * 16 + l15;
      vrd[dt][n] = d * 128 + (((2 * n + (lg >> 1)) ^ (d & 7)) << 4) + (lg & 1) * 8;
    }

  // ---- prologue: stage tile 0 into buffer 0 ----
  {
    char* kb = (char*)lds;
    char* vb0 = kb + 8192;
    gload16(kbase + ksrc[0], kb + tid * 16);
    gload16(kbase + ksrc[1], kb + (tid + 256) * 16);
    gload16(vtbase + vsrc[0], vb0 + tid * 16);
    gload16(vtbase + vsrc[1], vb0 + (tid + 256) * 16);
  }
  __syncthreads();   // drains vmcnt: tile 0 visible

  for (int t = 0; t < 64; ++t) {
    char* basec = (char*)lds + (t & 1) * 16384;
    // ---- issue tile t+1 loads into the other buffer (land during compute) ----
    if (t < 63) {
      char* basen = (char*)lds + ((t & 1) ^ 1) * 16384;
      const u16* kt = kbase + (t + 1) * 4096;
      const u16* vt = vtbase + (t + 1) * 64;
      gload16(kt + ksrc[0], basen + tid * 16);
      gload16(kt + ksrc[1], basen + (tid + 256) * 16);
      gload16(vt + vsrc[0], basen + 8192 + tid * 16);
      gload16(vt + vsrc[1], basen + 8192 + (tid + 256) * 16);
    }

    float4 bA[4];
#pragma unroll
    for (int n = 0; n < 4; ++n)
      bA[n] = *reinterpret_cast<const float4*>(bpt + n * 16);

    // ---- S^T = K Q^T, both q-groups share each K fragment ----
    f32x4 s0[4], s1[4];
    __builtin_amdgcn_s_setprio(1);
#pragma unroll
    for (int n = 0; n < 4; ++n) {
      bf16x8 k0f = *reinterpret_cast<const bf16x8*>(basec + krd[n][0]);
      bf16x8 k1f = *reinterpret_cast<const bf16x8*>(basec + krd[n][1]);
      f32x4 z0 = {};
      z0 = __builtin_amdgcn_mfma_f32_16x16x32_bf16(k0f, qf0[0], z0, 0, 0, 0);
      z0 = __builtin_amdgcn_mfma_f32_16x16x32_bf16(k1f, qf0[1], z0, 0, 0, 0);
      s0[n] = z0;
      f32x4 z1 = {};
      z1 = __builtin_amdgcn_mfma_f32_16x16x32_bf16(k0f, qf1[0], z1, 0, 0, 0);
      z1 = __builtin_amdgcn_mfma_f32_16x16x32_bf16(k1f, qf1[1], z1, 0, 0, 0);
      s1[n] = z1;
    }
    __builtin_amdgcn_s_setprio(0);

    // ---- fixed-max softmax ----
    bf16x4 pbf0[4], pbf1[4];
#pragma unroll
    for (int n = 0; n < 4; ++n) {
      float p0 = __builtin_amdgcn_exp2f(fmaf(s0[n][0], SCALE_LOG2E, bA[n].x));
      float p1 = __builtin_amdgcn_exp2f(fmaf(s0[n][1], SCALE_LOG2E, bA[n].y));
      float p2 = __builtin_amdgcn_exp2f(fmaf(s0[n][2], SCALE_LOG2E, bA[n].z));
      float p3 = __builtin_amdgcn_exp2f(fmaf(s0[n][3], SCALE_LOG2E, bA[n].w));
      lac0 += (p0 + p1) + (p2 + p3);
      union { unsigned u[2]; bf16x4 v; } uu;
      uu.u[0] = cvt_pk_bf16(p0, p1);
      uu.u[1] = cvt_pk_bf16(p2, p3);
      pbf0[n] = uu.v;
    }
#pragma unroll
    for (int n = 0; n < 4; ++n) {
      float p0 = __builtin_amdgcn_exp2f(fmaf(s1[n][0], SCALE_LOG2E, bA[n].x));
      float p1 = __builtin_amdgcn_exp2f(fmaf(s1[n][1], SCALE_LOG2E, bA[n].y));
      float p2 = __builtin_amdgcn_exp2f(fmaf(s1[n][2], SCALE_LOG2E, bA[n].z));
      float p3 = __builtin_amdgcn_exp2f(fmaf(s1[n][3], SCALE_LOG2E, bA[n].w));
      lac1 += (p0 + p1) + (p2 + p3);
      union { unsigned u[2]; bf16x4 v; } uu;
      uu.u[0] = cvt_pk_bf16(p0, p1);
      uu.u[1] = cvt_pk_bf16(p2, p3);
      pbf1[n] = uu.v;
    }

    // ---- O^T += V^T P^T ----
    char* vbc = basec + 8192;
    __builtin_amdgcn_s_setprio(1);
#pragma unroll
    for (int dt = 0; dt < 4; ++dt)
#pragma unroll
      for (int n = 0; n < 4; ++n) {
        bf16x4 va = *reinterpret_cast<const bf16x4*>(vbc + vrd[dt][n]);
        o0[dt] = __builtin_amdgcn_mfma_f32_16x16x16bf16_1k(va, pbf0[n], o0[dt], 0, 0, 0);
        o1[dt] = __builtin_amdgcn_mfma_f32_16x16x16bf16_1k(va, pbf1[n], o1[dt], 0, 0, 0);
      }
    __builtin_amdgcn_s_setprio(0);

    bpt += 64;
    __syncthreads();   // drains t+1 loads; releases basec for reuse
  }

  // ---- denominators: one cross-lane reduction for the whole kernel ----
  float lr0 = lac0;
  lr0 += __shfl_xor(lr0, 16, 64);
  lr0 += __shfl_xor(lr0, 32, 64);
  float lr1 = lac1;
  lr1 += __shfl_xor(lr1, 16, 64);
  lr1 += __shfl_xor(lr1, 32, 64);
  float rl0 = __builtin_amdgcn_rcpf(fmaxf(lr0, 1e-30f));
  float rl1 = __builtin_amdgcn_rcpf(fmaxf(lr1, 1e-30f));

  // ---- epilogue: normalize, transpose O^T -> O via LDS overlay, store ----
  u16 (*Es)[64] = reinterpret_cast<u16(*)[64]>(lds);
#pragma unroll
  for (int dt = 0; dt < 4; ++dt) {
    unsigned a0 = cvt_pk_bf16(o0[dt][0] * rl0, o0[dt][1] * rl0);
    unsigned a1 = cvt_pk_bf16(o0[dt][2] * rl0, o0[dt][3] * rl0);
    *reinterpret_cast<unsigned*>(&Es[w * 16 + l15][dt * 16 + lg * 4]) = a0;
    *reinterpret_cast<unsigned*>(&Es[w * 16 + l15][dt * 16 + lg * 4 + 2]) = a1;
    unsigned b0 = cvt_pk_bf16(o1[dt][0] * rl1, o1[dt][1] * rl1);
    unsigned b1 = cvt_pk_bf16(o1[dt][2] * rl1, o1[dt][3] * rl1);
    *reinterpret_cast<unsigned*>(&Es[64 + w * 16 + l15][dt * 16 + lg * 4]) = b0;
    *reinterpret_cast<unsigned*>(&Es[64 + w * 16 + l15][dt * 16 + lg * 4 + 2]) = b1;
  }
  asm volatile("s_waitcnt lgkmcnt(0)" ::: "memory");  // wave-local rows only
#pragma unroll
  for (int g = 0; g < 2; ++g) {
    int qr = lane >> 2, dc = (lane & 3) * 16;
    int lr = g * 64 + w * 16 + qr;
    uint4 x0 = *reinterpret_cast<const uint4*>(&Es[lr][dc]);
    uint4 x1 = *reinterpret_cast<const uint4*>(&Es[lr][dc + 8]);
    u16* dst = ao + ((size_t)b * 2048 + (size_t)qt * 128 + lr) * 1024 + h * 64 + dc;
    *reinterpret_cast<uint4*>(dst) = x0;
    *reinterpret_cast<uint4*>(dst + 8) = x1;
  }
}

// ---------------------------------------------------------------------------
// Output GEMM: out = ao(bf16) * Wp(bf16)^T + bp, fp32 out; gload_lds staging.
// ---------------------------------------------------------------------------
__global__ __launch_bounds__(256) void out_gemm(
    const u16* __restrict__ Abf, const u16* __restrict__ Wb,
    const float* __restrict__ bias, float* __restrict__ out)
{
  constexpr int K = 1024, N = 1024;
  __shared__ __align__(16) u16 As[128 * 32];
  __shared__ __align__(16) u16 Bs[128 * 32];
  const int tid = threadIdx.x;
  const int lane = tid & 63;
  const int w = tid >> 6;
  const int wm = w >> 1, wn = w & 1;
  const int bm = blockIdx.x, bn = blockIdx.y;
  const int l15 = lane & 15, lg = lane >> 4;

  f32x4 acc[4][4] = {};

  for (int k0 = 0; k0 < K; k0 += 32) {
    __syncthreads();
#pragma unroll
    for (int i = 0; i < 2; ++i) {
      int f = tid + 256 * i;
      int row = f >> 2, c = f & 3;
      gload16(Abf + (size_t)(bm * 128 + row) * K + k0 + c * 8, (char*)As + f * 16);
      gload16(Wb + (size_t)(bn * 128 + row) * K + k0 + c * 8, (char*)Bs + f * 16);
    }
    __syncthreads();

    bf16x8 af[4], bfr[4];
#pragma unroll
    for (int mi = 0; mi < 4; ++mi)
      af[mi] = *reinterpret_cast<const bf16x8*>((const char*)As + (wm * 64 + mi * 16 + l15) * 64 + lg * 16);
#pragma unroll
    for (int ni = 0; ni < 4; ++ni)
      bfr[ni] = *reinterpret_cast<const bf16x8*>((const char*)Bs + (wn * 64 + ni * 16 + l15) * 64 + lg * 16);
#pragma unroll
    for (int mi = 0; mi < 4; ++mi)
#pragma unroll
      for (int ni = 0; ni < 4; ++ni)
        acc[mi][ni] = __builtin_amdgcn_mfma_f32_16x16x32_bf16(af[mi], bfr[ni], acc[mi][ni], 0, 0, 0);
  }

#pragma unroll
  for (int mi = 0; mi < 4; ++mi)
#pragma unroll
    for (int ni = 0; ni < 4; ++ni)
#pragma unroll
      for (int r = 0; r < 4; ++r) {
        int m = bm * 128 + wm * 64 + mi * 16 + lg * 4 + r;
        int n = bn * 128 + wn * 64 + ni * 16 + l15;
        out[(size_t)m * N + n] = acc[mi][ni][r] + bias[n];
      }
}

// ---------------------------------------------------------------------------
extern "C" void kernel_launch(void* const* d_in, const int* in_sizes, int n_in,
                              void* d_out, int out_size, void* d_ws, size_t ws_size,
                              hipStream_t stream) {
  const float* q  = (const float*)d_in[0];
  const float* k  = (const float*)d_in[1];
  const float* v  = (const float*)d_in[2];
  const u8* mask_raw = (const u8*)d_in[3];
  const float* Wq = (const float*)d_in[4];
  const float* Wk = (const float*)d_in[5];
  const float* Wv = (const float*)d_in[6];
  const float* Wp = (const float*)d_in[7];
  const float* bp = (const float*)d_in[8];
  float* out = (float*)d_out;

  char* ws = (char*)d_ws;
  u16* qh = (u16*)(ws);                    //  8 MB: [2,16,2048,64] bf16
  u16* kh = (u16*)(ws + 8388608);          // 16 MB: [2,16,4096,64] bf16
  u16* vh = (u16*)(ws + 25165824);         // 16 MB: TRANSPOSED [2,16,64,4096] bf16
  u16* ao = (u16*)(ws + 41943040);         //  8 MB: [2,2048,1024] bf16
  float* biasf = (float*)(ws + 50331648);  // 32 KB: decoded mask bias (f32)
  u16* wqb = (u16*)(ws + 50364416);        //  2 MB each: bf16 weights
  u16* wkb = (u16*)(ws + 52461568);
  u16* wvb = (u16*)(ws + 54558720);
  u16* wpb = (u16*)(ws + 56655872);
  u16* qb  = (u16*)(ws + 58753024);        //  8 MB: q bf16
  u16* kb  = (u16*)(ws + 67141632);        // 16 MB: k bf16
  u16* vb  = (u16*)(ws + 83918848);        // 16 MB: v bf16
  const size_t need_full = 100696064;

  const bool full = ws_size >= need_full;
  cvt_all_k<<<2048, 256, 0, stream>>>(Wq, Wk, Wv, Wp, q, k, v,
                                      wqb, wkb, wvb, wpb, qb, kb, vb,
                                      full ? 3145728 : 524288);
  decode_mask_k<<<1, 256, 0, stream>>>(mask_raw, biasf, 8192);
  if (full) {
    proj_fused<true><<<1280, 256, 0, stream>>>(q, k, v, qb, kb, vb,
                                               wqb, wkb, wvb, qh, kh, vh);
  } else {
    proj_fused<false><<<1280, 256, 0, stream>>>(q, k, v, qb, kb, vb,
                                                wqb, wkb, wvb, qh, kh, vh);
  }
  attn_k<<<512, 256, 0, stream>>>(qh, kh, vh, biasf, ao);
  out_gemm<<<dim3(32, 8), 256, 0, stream>>>(ao, wpb, bp, out);
}

// Round 11
// 210.523 us; speedup vs baseline: 1.3304x; 1.3304x over previous
//
#include <hip/hip_runtime.h>

// ============================================================================
// CrossAttention fused: qkv proj (bf16 MFMA) -> flash attn -> out proj + bias
// B=2, NQ=2048, NK=4096, D=1024, H=16, HD=64, SCALE=0.125, mask-then-scale
//
// v12: revert v11 (transposed-V proj stores caused partial-line HBM writes;
// attn gload_lds variant was neutral-negative). Back to v10 GEMMs + v8 attn
// body. New: attn blocks merge TWO q-tiles (8 waves, 256 q-rows) sharing one
// KV staging stream (staged by waves 0-3 only) -> KV L2 fetch + staging work
// per CU halves; grid 256 = 1 block/CU, no tail. decode_mask merged into the
// convert kernel (one less launch).
// ============================================================================

typedef __attribute__((ext_vector_type(8))) short bf16x8;
typedef __attribute__((ext_vector_type(4))) short bf16x4;
typedef __attribute__((ext_vector_type(4))) float f32x4;
typedef __attribute__((ext_vector_type(4))) unsigned short u16x4;
typedef unsigned short u16;
typedef unsigned char u8;

#define DEV __device__ __forceinline__

DEV u16 f2bf(float f) {
  union { float f; unsigned int u; } x; x.f = f;
  unsigned int u = x.u;
  return (u16)((u + 0x7fffu + ((u >> 16) & 1u)) >> 16);
}

DEV unsigned cvt_pk_bf16(float lo, float hi) {
  unsigned r;
  asm("v_cvt_pk_bf16_f32 %0, %1, %2" : "=v"(r) : "v"(lo), "v"(hi));
  return r;
}

DEV u16x4 cvt4_bf16(float4 v) {
  union { unsigned u[2]; u16x4 s; } uu;
  uu.u[0] = cvt_pk_bf16(v.x, v.y);
  uu.u[1] = cvt_pk_bf16(v.z, v.w);
  return uu.s;
}

// async global->LDS, 16 bytes per lane; dst must be linear (base + lane*16)
DEV void gload16(const void* g, void* l) {
  __builtin_amdgcn_global_load_lds(
      (const __attribute__((address_space(1))) void*)g,
      (__attribute__((address_space(3))) void*)l, 16, 0, 0);
}

// mask-then-scale in log2 domain; fixed softmax shift M=16 folded into bias.
#define MASK_BIAS (-1.8033688e19f)
#define FREE_BIAS (-16.0f)
#define SCALE_LOG2E 0.18033688f

// ---------------------------------------------------------------------------
// Prep: bulk fp32->bf16 convert (blocks 0..N-2) + mask decode (last block).
// ---------------------------------------------------------------------------
__global__ void prep_k(
    const float* __restrict__ Wq, const float* __restrict__ Wk,
    const float* __restrict__ Wv, const float* __restrict__ Wp,
    const float* __restrict__ q, const float* __restrict__ k, const float* __restrict__ v,
    u16* __restrict__ wqb, u16* __restrict__ wkb, u16* __restrict__ wvb, u16* __restrict__ wpb,
    u16* __restrict__ qb, u16* __restrict__ kb, u16* __restrict__ vb, int total,
    const u8* __restrict__ raw, float* __restrict__ biasf)
{
  if (blockIdx.x == gridDim.x - 1) {
    // ---- mask decode: fingerprint storage dtype, expand to log2-bias ----
    int t = threadIdx.x;
    int f_off = 0, f_gt1 = 0, f_80 = 0;
    for (int i = t; i < 8192; i += 256) {
      u8 bv = raw[i];
      if (bv > 1) f_gt1 = 1;
      if ((i & 3) && bv) f_off = 1;
      if (((i & 3) == 0) && bv == 0x80) f_80 = 1;
    }
    int g_gt1 = __syncthreads_or(f_gt1);
    int g_off = __syncthreads_or(f_off);
    int g_80  = __syncthreads_or(f_80);
    for (int i = t; i < 8192; i += 256) {
      int vv;
      if (g_gt1) {
        if (g_80) vv = (((const u16*)raw)[i] != 0) ? 1 : 0;      // bf16 storage
        else      vv = (((const float*)raw)[i] != 0.0f) ? 1 : 0; // f32 storage
      } else if (g_off) {
        vv = raw[i] ? 1 : 0;                                     // bool/u8 storage
      } else {
        vv = (((const int*)raw)[i] != 0) ? 1 : 0;                // int32 storage
      }
      biasf[i] = vv ? MASK_BIAS : FREE_BIAS;
    }
    return;
  }
  int stride = (gridDim.x - 1) * blockDim.x;
  for (int idx = blockIdx.x * blockDim.x + threadIdx.x; idx < total; idx += stride) {
    const float* src; u16* dst; int off;
    if (idx < 131072)       { src = Wq; dst = wqb; off = idx; }
    else if (idx < 262144)  { src = Wk; dst = wkb; off = idx - 131072; }
    else if (idx < 393216)  { src = Wv; dst = wvb; off = idx - 262144; }
    else if (idx < 524288)  { src = Wp; dst = wpb; off = idx - 393216; }
    else if (idx < 1048576) { src = q;  dst = qb;  off = idx - 524288; }
    else if (idx < 2097152) { src = k;  dst = kb;  off = idx - 1048576; }
    else                    { src = v;  dst = vb;  off = idx - 2097152; }
    float4 a = *reinterpret_cast<const float4*>(src + (size_t)off * 8);
    float4 bq = *reinterpret_cast<const float4*>(src + (size_t)off * 8 + 4);
    union { unsigned u[4]; uint4 q4; } o;
    o.u[0] = cvt_pk_bf16(a.x, a.y); o.u[1] = cvt_pk_bf16(a.z, a.w);
    o.u[2] = cvt_pk_bf16(bq.x, bq.y); o.u[3] = cvt_pk_bf16(bq.z, bq.w);
    *reinterpret_cast<uint4*>(dst + (size_t)off * 8) = o.q4;
  }
}

// ---------------------------------------------------------------------------
// Fused QKV projection GEMM (v10, reverted). Grid 1280: q / k / v segments.
// 128x128 tile, BK=32, 4 waves, global_load_lds staging (linear LDS).
// Output bf16 head layout [b,h,seq,64].
// ---------------------------------------------------------------------------
template <bool ABF>
__global__ __launch_bounds__(256) void proj_fused(
    const float* __restrict__ qf32, const float* __restrict__ kf32, const float* __restrict__ vf32,
    const u16* __restrict__ qb, const u16* __restrict__ kb, const u16* __restrict__ vb,
    const u16* __restrict__ wqb, const u16* __restrict__ wkb, const u16* __restrict__ wvb,
    u16* __restrict__ qh, u16* __restrict__ kh, u16* __restrict__ vh)
{
  constexpr int K = 1024;
  __shared__ __align__(16) u16 As[128 * 32];   // linear, 64 B rows
  __shared__ __align__(16) u16 Bs[128 * 32];
  const int tid = threadIdx.x;
  const int lane = tid & 63;
  const int w = tid >> 6;
  const int wm = w >> 1, wn = w & 1;
  const int l15 = lane & 15, lg = lane >> 4;

  int bid = blockIdx.x;
  bid = (bid & 7) * 160 + (bid >> 3);
  int seg, local;
  if (bid < 256)      { seg = 0; local = bid; }
  else if (bid < 768) { seg = 1; local = bid - 256; }
  else                { seg = 2; local = bid - 768; }
  const int bm = local >> 3, bn = local & 7;
  const float* Af = seg == 0 ? qf32 : (seg == 1 ? kf32 : vf32);
  const u16* Ab   = seg == 0 ? qb   : (seg == 1 ? kb   : vb);
  const u16* Wb   = seg == 0 ? wqb  : (seg == 1 ? wkb  : wvb);
  u16* outh       = seg == 0 ? qh   : (seg == 1 ? kh   : vh);
  const int sl = (seg == 0) ? 11 : 12;

  f32x4 acc[4][4] = {};

  for (int k0 = 0; k0 < K; k0 += 32) {
    __syncthreads();
    if constexpr (ABF) {
#pragma unroll
      for (int i = 0; i < 2; ++i) {
        int f = tid + 256 * i;
        int row = f >> 2, c = f & 3;
        gload16(Ab + (size_t)(bm * 128 + row) * K + k0 + c * 8, (char*)As + f * 16);
        gload16(Wb + (size_t)(bn * 128 + row) * K + k0 + c * 8, (char*)Bs + f * 16);
      }
    } else {
#pragma unroll
      for (int i = 0; i < 2; ++i) {
        int f = tid + 256 * i;
        int row = f >> 2, c = f & 3;
        gload16(Wb + (size_t)(bn * 128 + row) * K + k0 + c * 8, (char*)Bs + f * 16);
      }
#pragma unroll
      for (int i = 0; i < 4; ++i) {
        int f = tid + 256 * i;
        int row = f >> 3, c4 = f & 7;
        float4 va = *reinterpret_cast<const float4*>(Af + (size_t)(bm * 128 + row) * K + k0 + c4 * 4);
        *reinterpret_cast<u16x4*>((char*)As + row * 64 + c4 * 8) = cvt4_bf16(va);
      }
    }
    __syncthreads();

    bf16x8 af[4], bfr[4];
#pragma unroll
    for (int mi = 0; mi < 4; ++mi)
      af[mi] = *reinterpret_cast<const bf16x8*>((const char*)As + (wm * 64 + mi * 16 + l15) * 64 + lg * 16);
#pragma unroll
    for (int ni = 0; ni < 4; ++ni)
      bfr[ni] = *reinterpret_cast<const bf16x8*>((const char*)Bs + (wn * 64 + ni * 16 + l15) * 64 + lg * 16);
#pragma unroll
    for (int mi = 0; mi < 4; ++mi)
#pragma unroll
      for (int ni = 0; ni < 4; ++ni)
        acc[mi][ni] = __builtin_amdgcn_mfma_f32_16x16x32_bf16(af[mi], bfr[ni], acc[mi][ni], 0, 0, 0);
  }

  const int seqmask = (1 << sl) - 1;
#pragma unroll
  for (int mi = 0; mi < 4; ++mi)
#pragma unroll
    for (int ni = 0; ni < 4; ++ni)
#pragma unroll
      for (int r = 0; r < 4; ++r) {
        int m = bm * 128 + wm * 64 + mi * 16 + lg * 4 + r;
        int n = bn * 128 + wn * 64 + ni * 16 + l15;
        int b = m >> sl, ml = m & seqmask;
        int h = n >> 6, hd = n & 63;
        outh[((((size_t)b * 16 + h) << sl) + ml) * 64 + hd] = f2bf(acc[mi][ni][r]);
      }
}

// ---------------------------------------------------------------------------
// Flash attention v12. 1 block = (b, h, 256-row q-tile); 8 waves x 32 q-rows
// (two 16-row groups each). ONE KV staging stream (waves 0-3, v8 code) feeds
// all 8 waves -> KV fetch + staging per CU halves vs two 4-wave blocks.
// Grid 256 = 1 block/CU. v8 body otherwise: swapped QK^T, fixed-max softmax,
// K Ks[64][72], V Vt 136B rows + 8B XOR, double-buffered LDS, 1 barrier/tile.
// ---------------------------------------------------------------------------
__global__ __launch_bounds__(512, 2) void attn_k(
    const u16* __restrict__ qh, const u16* __restrict__ kh, const u16* __restrict__ vh,
    const float* __restrict__ biasf, u16* __restrict__ ao)
{
  // Two buffers of (Ks 64x72 u16 = 9216 B ; Vt 64 rows * 136 B = 8704 B).
  __shared__ __align__(16) u16 lds[17920];

  const int tid = threadIdx.x;
  const int lane = tid & 63;
  const int w = tid >> 6;          // 0..7
  const int l15 = lane & 15, lg = lane >> 4;

  // XCD-aware swizzle (256 blocks, grid % 8 == 0 -> bijective)
  int bid = blockIdx.x;
  bid = (bid & 7) * 32 + (bid >> 3);
  const int qt = bid & 7;        // 8 q-tiles of 256 rows
  const int bh = bid >> 3;       // 0..31 = b*16 + h
  const int b = bh >> 4, h = bh & 15;

  const size_t base_kv = (size_t)bh * 4096 * 64;

  // Q fragments for both groups, direct from global
  bf16x8 qf0[2], qf1[2];
  {
    const u16* qp0 = qh + ((size_t)bh * 2048 + (size_t)qt * 256 + w * 16 + l15) * 64 + lg * 8;
    qf0[0] = *reinterpret_cast<const bf16x8*>(qp0);
    qf0[1] = *reinterpret_cast<const bf16x8*>(qp0 + 32);
    const u16* qp1 = qp0 + 128 * 64;   // +128 q-rows
    qf1[0] = *reinterpret_cast<const bf16x8*>(qp1);
    qf1[1] = *reinterpret_cast<const bf16x8*>(qp1 + 32);
  }

  f32x4 o0[4] = {}, o1[4] = {};    // O^T[d = dt*16+lg*4+r][q = l15]
  float lac0 = 0.f, lac1 = 0.f;    // lane-local denominator partials
  const float* bpt = biasf + b * 4096 + lg * 4;

  // staging assignments (threads 0..255 = waves 0..3 only)
  const int kp = tid >> 3, c8v = tid & 7;
  const u16* kg = kh + base_kv + (size_t)tid * 8;
  const u16* vg = vh + base_kv + (size_t)(2 * kp) * 64 + c8v * 8;
  const int kcol = (tid & 7) * 8;
  const int krow0 = tid >> 3, krow1 = krow0 + 32;
  int vst[8];
#pragma unroll
  for (int j = 0; j < 8; ++j) {
    int d = c8v * 8 + j;
    vst[j] = (d * 136 + kp * 4) ^ (((d >> 3) & 7) << 3);
  }
  // read offsets (all waves)
  int vrd[4][4];
#pragma unroll
  for (int dt = 0; dt < 4; ++dt)
#pragma unroll
    for (int n = 0; n < 4; ++n) {
      int d = dt * 16 + l15;
      vrd[dt][n] = ((d * 136 + (n * 16 + lg * 4) * 2)) ^ (((d >> 3) & 7) << 3);
    }

  // ---- prologue: stage tile 0 into buf0, prefetch tile 1 regs (waves 0-3) --
  uint4 kr0, kr1, vr0, vr1;
  if (w < 4) {
    kr0 = *reinterpret_cast<const uint4*>(kg);
    kr1 = *reinterpret_cast<const uint4*>(kg + 2048);
    vr0 = *reinterpret_cast<const uint4*>(vg);
    vr1 = *reinterpret_cast<const uint4*>(vg + 64);
    u16 (*K0)[72] = reinterpret_cast<u16(*)[72]>(lds);
    u16* V0 = lds + 4608;
    *reinterpret_cast<uint4*>(&K0[krow0][kcol]) = kr0;
    *reinterpret_cast<uint4*>(&K0[krow1][kcol]) = kr1;
    const u16* pa = reinterpret_cast<const u16*>(&vr0);
    const u16* pb = reinterpret_cast<const u16*>(&vr1);
#pragma unroll
    for (int j = 0; j < 8; ++j) {
      ushort2 t2; t2.x = pa[j]; t2.y = pb[j];
      *reinterpret_cast<ushort2*>(reinterpret_cast<char*>(V0) + vst[j]) = t2;
    }
    kg += 4096; vg += 4096;
    kr0 = *reinterpret_cast<const uint4*>(kg);
    kr1 = *reinterpret_cast<const uint4*>(kg + 2048);
    vr0 = *reinterpret_cast<const uint4*>(vg);
    vr1 = *reinterpret_cast<const uint4*>(vg + 64);
  }
  __syncthreads();

  for (int t = 0; t < 64; ++t) {
    u16* bufc = lds + (t & 1) * 8960;
    u16 (*Ks)[72] = reinterpret_cast<u16(*)[72]>(bufc);
    u16* Vt = bufc + 4608;

    // ---- stage tile t+1 into the other buffer; prefetch tile t+2 ----
    if (w < 4 && t < 63) {
      u16* bufn = lds + ((t & 1) ^ 1) * 8960;
      u16 (*Kn)[72] = reinterpret_cast<u16(*)[72]>(bufn);
      u16* Vn = bufn + 4608;
      *reinterpret_cast<uint4*>(&Kn[krow0][kcol]) = kr0;
      *reinterpret_cast<uint4*>(&Kn[krow1][kcol]) = kr1;
      const u16* pa = reinterpret_cast<const u16*>(&vr0);
      const u16* pb = reinterpret_cast<const u16*>(&vr1);
#pragma unroll
      for (int j = 0; j < 8; ++j) {
        ushort2 t2; t2.x = pa[j]; t2.y = pb[j];
        *reinterpret_cast<ushort2*>(reinterpret_cast<char*>(Vn) + vst[j]) = t2;
      }
      if (t < 62) {
        kg += 4096; vg += 4096;
        kr0 = *reinterpret_cast<const uint4*>(kg);
        kr1 = *reinterpret_cast<const uint4*>(kg + 2048);
        vr0 = *reinterpret_cast<const uint4*>(vg);
        vr1 = *reinterpret_cast<const uint4*>(vg + 64);
      }
    }

    // bias (shared by both q-groups)
    float4 bA[4];
#pragma unroll
    for (int n = 0; n < 4; ++n)
      bA[n] = *reinterpret_cast<const float4*>(bpt + n * 16);

    // ---- S^T = K Q^T, both q-groups share each K fragment ----
    f32x4 s0[4], s1[4];
    __builtin_amdgcn_s_setprio(1);
#pragma unroll
    for (int n = 0; n < 4; ++n) {
      bf16x8 k0f = *reinterpret_cast<const bf16x8*>(&Ks[n * 16 + l15][lg * 8]);
      bf16x8 k1f = *reinterpret_cast<const bf16x8*>(&Ks[n * 16 + l15][32 + lg * 8]);
      f32x4 z0 = {};
      z0 = __builtin_amdgcn_mfma_f32_16x16x32_bf16(k0f, qf0[0], z0, 0, 0, 0);
      z0 = __builtin_amdgcn_mfma_f32_16x16x32_bf16(k1f, qf0[1], z0, 0, 0, 0);
      s0[n] = z0;
      f32x4 z1 = {};
      z1 = __builtin_amdgcn_mfma_f32_16x16x32_bf16(k0f, qf1[0], z1, 0, 0, 0);
      z1 = __builtin_amdgcn_mfma_f32_16x16x32_bf16(k1f, qf1[1], z1, 0, 0, 0);
      s1[n] = z1;
    }
    __builtin_amdgcn_s_setprio(0);

    // ---- fixed-max softmax: p = exp2(s*c + bias), lane-local l sum ----
    bf16x4 pbf0[4], pbf1[4];
#pragma unroll
    for (int n = 0; n < 4; ++n) {
      float p0 = __builtin_amdgcn_exp2f(fmaf(s0[n][0], SCALE_LOG2E, bA[n].x));
      float p1 = __builtin_amdgcn_exp2f(fmaf(s0[n][1], SCALE_LOG2E, bA[n].y));
      float p2 = __builtin_amdgcn_exp2f(fmaf(s0[n][2], SCALE_LOG2E, bA[n].z));
      float p3 = __builtin_amdgcn_exp2f(fmaf(s0[n][3], SCALE_LOG2E, bA[n].w));
      lac0 += (p0 + p1) + (p2 + p3);
      union { unsigned u[2]; bf16x4 v; } uu;
      uu.u[0] = cvt_pk_bf16(p0, p1);
      uu.u[1] = cvt_pk_bf16(p2, p3);
      pbf0[n] = uu.v;
    }
#pragma unroll
    for (int n = 0; n < 4; ++n) {
      float p0 = __builtin_amdgcn_exp2f(fmaf(s1[n][0], SCALE_LOG2E, bA[n].x));
      float p1 = __builtin_amdgcn_exp2f(fmaf(s1[n][1], SCALE_LOG2E, bA[n].y));
      float p2 = __builtin_amdgcn_exp2f(fmaf(s1[n][2], SCALE_LOG2E, bA[n].z));
      float p3 = __builtin_amdgcn_exp2f(fmaf(s1[n][3], SCALE_LOG2E, bA[n].w));
      lac1 += (p0 + p1) + (p2 + p3);
      union { unsigned u[2]; bf16x4 v; } uu;
      uu.u[0] = cvt_pk_bf16(p0, p1);
      uu.u[1] = cvt_pk_bf16(p2, p3);
      pbf1[n] = uu.v;
    }

    // ---- O^T += V^T P^T, each V fragment feeds both q-groups ----
    __builtin_amdgcn_s_setprio(1);
#pragma unroll
    for (int dt = 0; dt < 4; ++dt)
#pragma unroll
      for (int n = 0; n < 4; ++n) {
        bf16x4 va = *reinterpret_cast<const bf16x4*>(
            reinterpret_cast<char*>(Vt) + vrd[dt][n]);
        o0[dt] = __builtin_amdgcn_mfma_f32_16x16x16bf16_1k(va, pbf0[n], o0[dt], 0, 0, 0);
        o1[dt] = __builtin_amdgcn_mfma_f32_16x16x16bf16_1k(va, pbf1[n], o1[dt], 0, 0, 0);
      }
    __builtin_amdgcn_s_setprio(0);

    bpt += 64;
    __syncthreads();   // staged writes visible; buf roles swap
  }

  // ---- denominators: one cross-lane reduction for the whole kernel ----
  float lr0 = lac0;
  lr0 += __shfl_xor(lr0, 16, 64);
  lr0 += __shfl_xor(lr0, 32, 64);
  float lr1 = lac1;
  lr1 += __shfl_xor(lr1, 16, 64);
  lr1 += __shfl_xor(lr1, 32, 64);
  float rl0 = __builtin_amdgcn_rcpf(fmaxf(lr0, 1e-30f));
  float rl1 = __builtin_amdgcn_rcpf(fmaxf(lr1, 1e-30f));

  // ---- epilogue: normalize, transpose O^T -> O via LDS overlay, store ----
  // Es[256][64] = 32768 B <= 35840 B. Rows: g0 = w*16+l15, g1 = 128+w*16+l15.
  u16 (*Es)[64] = reinterpret_cast<u16(*)[64]>(lds);
#pragma unroll
  for (int dt = 0; dt < 4; ++dt) {
    unsigned a0 = cvt_pk_bf16(o0[dt][0] * rl0, o0[dt][1] * rl0);
    unsigned a1 = cvt_pk_bf16(o0[dt][2] * rl0, o0[dt][3] * rl0);
    *reinterpret_cast<unsigned*>(&Es[w * 16 + l15][dt * 16 + lg * 4]) = a0;
    *reinterpret_cast<unsigned*>(&Es[w * 16 + l15][dt * 16 + lg * 4 + 2]) = a1;
    unsigned b0 = cvt_pk_bf16(o1[dt][0] * rl1, o1[dt][1] * rl1);
    unsigned b1 = cvt_pk_bf16(o1[dt][2] * rl1, o1[dt][3] * rl1);
    *reinterpret_cast<unsigned*>(&Es[128 + w * 16 + l15][dt * 16 + lg * 4]) = b0;
    *reinterpret_cast<unsigned*>(&Es[128 + w * 16 + l15][dt * 16 + lg * 4 + 2]) = b1;
  }
  asm volatile("s_waitcnt lgkmcnt(0)" ::: "memory");  // wave-local rows only
#pragma unroll
  for (int g = 0; g < 2; ++g) {
    int qr = lane >> 2, dc = (lane & 3) * 16;
    int lr = g * 128 + w * 16 + qr;
    uint4 x0 = *reinterpret_cast<const uint4*>(&Es[lr][dc]);
    uint4 x1 = *reinterpret_cast<const uint4*>(&Es[lr][dc + 8]);
    u16* dst = ao + ((size_t)b * 2048 + (size_t)qt * 256 + lr) * 1024 + h * 64 + dc;
    *reinterpret_cast<uint4*>(dst) = x0;
    *reinterpret_cast<uint4*>(dst + 8) = x1;
  }
}

// ---------------------------------------------------------------------------
// Output GEMM (v10, reverted): out = ao(bf16) * Wp(bf16)^T + bp, fp32 out.
// ---------------------------------------------------------------------------
__global__ __launch_bounds__(256) void out_gemm(
    const u16* __restrict__ Abf, const u16* __restrict__ Wb,
    const float* __restrict__ bias, float* __restrict__ out)
{
  constexpr int K = 1024, N = 1024;
  __shared__ __align__(16) u16 As[128 * 32];
  __shared__ __align__(16) u16 Bs[128 * 32];
  const int tid = threadIdx.x;
  const int lane = tid & 63;
  const int w = tid >> 6;
  const int wm = w >> 1, wn = w & 1;
  const int bm = blockIdx.x, bn = blockIdx.y;
  const int l15 = lane & 15, lg = lane >> 4;

  f32x4 acc[4][4] = {};

  for (int k0 = 0; k0 < K; k0 += 32) {
    __syncthreads();
#pragma unroll
    for (int i = 0; i < 2; ++i) {
      int f = tid + 256 * i;
      int row = f >> 2, c = f & 3;
      gload16(Abf + (size_t)(bm * 128 + row) * K + k0 + c * 8, (char*)As + f * 16);
      gload16(Wb + (size_t)(bn * 128 + row) * K + k0 + c * 8, (char*)Bs + f * 16);
    }
    __syncthreads();

    bf16x8 af[4], bfr[4];
#pragma unroll
    for (int mi = 0; mi < 4; ++mi)
      af[mi] = *reinterpret_cast<const bf16x8*>((const char*)As + (wm * 64 + mi * 16 + l15) * 64 + lg * 16);
#pragma unroll
    for (int ni = 0; ni < 4; ++ni)
      bfr[ni] = *reinterpret_cast<const bf16x8*>((const char*)Bs + (wn * 64 + ni * 16 + l15) * 64 + lg * 16);
#pragma unroll
    for (int mi = 0; mi < 4; ++mi)
#pragma unroll
      for (int ni = 0; ni < 4; ++ni)
        acc[mi][ni] = __builtin_amdgcn_mfma_f32_16x16x32_bf16(af[mi], bfr[ni], acc[mi][ni], 0, 0, 0);
  }

#pragma unroll
  for (int mi = 0; mi < 4; ++mi)
#pragma unroll
    for (int ni = 0; ni < 4; ++ni)
#pragma unroll
      for (int r = 0; r < 4; ++r) {
        int m = bm * 128 + wm * 64 + mi * 16 + lg * 4 + r;
        int n = bn * 128 + wn * 64 + ni * 16 + l15;
        out[(size_t)m * N + n] = acc[mi][ni][r] + bias[n];
      }
}

// ---------------------------------------------------------------------------
extern "C" void kernel_launch(void* const* d_in, const int* in_sizes, int n_in,
                              void* d_out, int out_size, void* d_ws, size_t ws_size,
                              hipStream_t stream) {
  const float* q  = (const float*)d_in[0];
  const float* k  = (const float*)d_in[1];
  const float* v  = (const float*)d_in[2];
  const u8* mask_raw = (const u8*)d_in[3];
  const float* Wq = (const float*)d_in[4];
  const float* Wk = (const float*)d_in[5];
  const float* Wv = (const float*)d_in[6];
  const float* Wp = (const float*)d_in[7];
  const float* bp = (const float*)d_in[8];
  float* out = (float*)d_out;

  char* ws = (char*)d_ws;
  u16* qh = (u16*)(ws);                    //  8 MB: [2,16,2048,64] bf16
  u16* kh = (u16*)(ws + 8388608);          // 16 MB: [2,16,4096,64] bf16
  u16* vh = (u16*)(ws + 25165824);         // 16 MB: [2,16,4096,64] bf16
  u16* ao = (u16*)(ws + 41943040);         //  8 MB: [2,2048,1024] bf16
  float* biasf = (float*)(ws + 50331648);  // 32 KB: decoded mask bias (f32)
  u16* wqb = (u16*)(ws + 50364416);        //  2 MB each: bf16 weights
  u16* wkb = (u16*)(ws + 52461568);
  u16* wvb = (u16*)(ws + 54558720);
  u16* wpb = (u16*)(ws + 56655872);
  u16* qb  = (u16*)(ws + 58753024);        //  8 MB: q bf16
  u16* kb  = (u16*)(ws + 67141632);        // 16 MB: k bf16
  u16* vb  = (u16*)(ws + 83918848);        // 16 MB: v bf16
  const size_t need_full = 100696064;

  const bool full = ws_size >= need_full;
  prep_k<<<2049, 256, 0, stream>>>(Wq, Wk, Wv, Wp, q, k, v,
                                   wqb, wkb, wvb, wpb, qb, kb, vb,
                                   full ? 3145728 : 524288, mask_raw, biasf);
  if (full) {
    proj_fused<true><<<1280, 256, 0, stream>>>(q, k, v, qb, kb, vb,
                                               wqb, wkb, wvb, qh, kh, vh);
  } else {
    proj_fused<false><<<1280, 256, 0, stream>>>(q, k, v, qb, kb, vb,
                                                wqb, wkb, wvb, qh, kh, vh);
  }
  attn_k<<<256, 512, 0, stream>>>(qh, kh, vh, biasf, ao);
  out_gemm<<<dim3(32, 8), 256, 0, stream>>>(ao, wpb, bp, out);
}